// Round 7
// baseline (38829.434 us; speedup 1.0000x reference)
//
#include <hip/hip_runtime.h>
#include <cstddef>

#define DEV static __device__ __forceinline__
typedef unsigned long long ull;

DEV float b2f(unsigned short u){ unsigned int i=((unsigned int)u)<<16; float f; __builtin_memcpy(&f,&i,4); return f; }
DEV float lo16(unsigned int u){ unsigned int i=u<<16; float f; __builtin_memcpy(&f,&i,4); return f; }
DEV float hi16(unsigned int u){ unsigned int i=u&0xffff0000u; float f; __builtin_memcpy(&f,&i,4); return f; }
DEV unsigned short f2b(float f){ unsigned int i; __builtin_memcpy(&i,&f,4); unsigned int r=(i+0x7fffu+((i>>16)&1u))>>16; return (unsigned short)r; }
DEV float sigf(float x){ return 1.f/(1.f+__expf(-x)); }
DEV float eluf(float x){ return x>0.f ? x : (__expf(x)-1.f); }
DEV float gload(const void* p, long i, int f32){
  return f32 ? ((const float*)p)[i] : b2f(((const unsigned short*)p)[i]);
}
// tagged-word mailbox: relaxed agent atomics (LLC point, no L2 invalidation)
DEV ull pk(float f, unsigned tag){ unsigned b; __builtin_memcpy(&b,&f,4); return ((ull)tag<<32)|b; }
DEV float upk(ull u){ unsigned b=(unsigned)u; float f; __builtin_memcpy(&f,&b,4); return f; }
DEV ull pk2(float a, float b, unsigned tag){ return ((ull)tag<<32) | ((ull)f2b(a)<<16) | (ull)f2b(b); }
DEV void ast64(ull* p, ull v){ __hip_atomic_store(p, v, __ATOMIC_RELAXED, __HIP_MEMORY_SCOPE_AGENT); }
DEV ull ald64(const ull* p){ return __hip_atomic_load(p, __ATOMIC_RELAXED, __HIP_MEMORY_SCOPE_AGENT); }

// ---------------------------------------------------------------------------
// Sniff input dtypes. flags[0]=1 if floats are f32; flags[1]=1 if ints are i64.
// ---------------------------------------------------------------------------
__global__ __launch_bounds__(64) void sniff(const void* __restrict__ seqs,
                                            const void* __restrict__ seq_lens,
                                            int* __restrict__ flags)
{
  __shared__ int cnt;
  if (threadIdx.x==0) cnt=0;
  __syncthreads();
  const unsigned short* u = (const unsigned short*)seqs;
  int sane=0;
  for (int i=threadIdx.x;i<1024;i+=64){
    int e = (u[i]>>7)&0xFF;
    if (e>=0x70 && e<=0x8F) sane++;
  }
  atomicAdd(&cnt, sane);
  __syncthreads();
  if (threadIdx.x==0){
    flags[0] = (cnt < 820) ? 1 : 0;
    const int* s = (const int*)seq_lens;
    flags[1] = ((s[1]|s[3]|s[5]|s[7])==0) ? 1 : 0;
  }
}

// ---------------------------------------------------------------------------
// Prep: 8-part-sliced bf16 weights.
// Wl[l][p∈8][k∈512][gi∈128]: g = (gi>>5)*256 + p*32 + (gi&31);
// k<256 -> ih (ctx/h_in) col k, k>=256 -> hh col k-256.
// ---------------------------------------------------------------------------
__global__ __launch_bounds__(256) void prep_transpose(
    const void* __restrict__ Wih0, const void* __restrict__ Whh0,
    const void* __restrict__ Wih1, const void* __restrict__ Whh1,
    const void* __restrict__ Wih2, const void* __restrict__ Whh2,
    const void* __restrict__ kW0,  const void* __restrict__ kW1,
    const void* __restrict__ vW0,  const void* __restrict__ vW1,
    const void* __restrict__ qW0,  const void* __restrict__ qW1,
    const void* __restrict__ bih0, const void* __restrict__ bhh0,
    const void* __restrict__ bih1, const void* __restrict__ bhh1,
    const void* __restrict__ bih2, const void* __restrict__ bhh2,
    const void* __restrict__ outW, const void* __restrict__ inith,
    const void* __restrict__ initc, const void* __restrict__ qb0,
    const void* __restrict__ qb1,  const void* __restrict__ outb,
    const int* __restrict__ flags,
    unsigned short* __restrict__ Wl0, unsigned short* __restrict__ Wl1,
    unsigned short* __restrict__ Wl2,
    unsigned short* __restrict__ kW0T, unsigned short* __restrict__ kW1T,
    unsigned short* __restrict__ vW0T, unsigned short* __restrict__ vW1T,
    unsigned short* __restrict__ qW0T, unsigned short* __restrict__ qW1T,
    float* __restrict__ bsum,
    unsigned short* __restrict__ outWc, unsigned short* __restrict__ inithc,
    unsigned short* __restrict__ initcc, unsigned short* __restrict__ qb0c,
    unsigned short* __restrict__ qb1c,  unsigned short* __restrict__ outbc)
{
  const int f32 = flags[0];
  int idx = blockIdx.x*256 + threadIdx.x;
  if (idx < 524288){ int pp=idx>>16, r=idx&65535, k=r>>7, gi=r&127;
    int g = ((gi>>5)<<8) + (pp<<5) + (gi&31);
    Wl0[idx] = f2b((k<256)? gload(Wih0,(long)g*512+k,f32) : gload(Whh0,(long)g*256+(k-256),f32)); return; }
  idx -= 524288;
  if (idx < 524288){ int pp=idx>>16, r=idx&65535, k=r>>7, gi=r&127;
    int g = ((gi>>5)<<8) + (pp<<5) + (gi&31);
    Wl1[idx] = f2b((k<256)? gload(Wih1,(long)g*256+k,f32) : gload(Whh1,(long)g*256+(k-256),f32)); return; }
  idx -= 524288;
  if (idx < 524288){ int pp=idx>>16, r=idx&65535, k=r>>7, gi=r&127;
    int g = ((gi>>5)<<8) + (pp<<5) + (gi&31);
    Wl2[idx] = f2b((k<256)? gload(Wih2,(long)g*256+k,f32) : gload(Whh2,(long)g*256+(k-256),f32)); return; }
  idx -= 524288;
  if (idx < 262144){ int k=idx>>9, j=idx&511; kW0T[idx]=f2b(gload(kW0,(long)j*512+k,f32)); return; }
  idx -= 262144;
  if (idx < 32768){ int k=idx>>6, j=idx&63; kW1T[idx]=f2b(gload(kW1,(long)j*512+k,f32)); return; }
  idx -= 32768;
  if (idx < 131072){ int k=idx>>8, j=idx&255; vW0T[idx]=f2b(gload(vW0,(long)j*512+k,f32)); return; }
  idx -= 131072;
  if (idx < 65536){ int k=idx>>8, j=idx&255; vW1T[idx]=f2b(gload(vW1,(long)j*256+k,f32)); return; }
  idx -= 65536;
  if (idx < 65536){ int k=idx>>8, j=idx&255; qW0T[idx]=f2b(gload(qW0,(long)j*256+k,f32)); return; }
  idx -= 65536;
  if (idx < 16384){ int k=idx>>6, j=idx&63; qW1T[idx]=f2b(gload(qW1,(long)j*256+k,f32)); return; }
  idx -= 16384;
  if (idx < 3072){ int l=idx>>10, r=idx&1023, pp=r>>7, gi=r&127;
    int g = ((gi>>5)<<8) + (pp<<5) + (gi&31);
    const void* bi = (l==0)?bih0:((l==1)?bih1:bih2);
    const void* bh = (l==0)?bhh0:((l==1)?bhh1:bhh2);
    bsum[idx] = gload(bi,g,f32)+gload(bh,g,f32); return; }
  idx -= 3072;
  if (idx < 17408){ outWc[idx]=f2b(gload(outW,idx,f32)); return; }
  idx -= 17408;
  if (idx < 768){ inithc[idx]=f2b(gload(inith,idx,f32)); return; }
  idx -= 768;
  if (idx < 768){ initcc[idx]=f2b(gload(initc,idx,f32)); return; }
  idx -= 768;
  if (idx < 256){ qb0c[idx]=f2b(gload(qb0,idx,f32)); return; }
  idx -= 256;
  if (idx < 64){ qb1c[idx]=f2b(gload(qb1,idx,f32)); return; }
  idx -= 64;
  if (idx < 34){ outbc[idx]=f2b(gload(outb,idx,f32)); return; }
}

// gep[p∈8][v][gi∈128] = sum_k emb[v][k] * Wih0[g(p,gi)][256+k]
__global__ __launch_bounds__(256) void prep_ge(
    const void* __restrict__ emb,
    const void* __restrict__ Wih0,
    const int* __restrict__ flags,
    float* __restrict__ gep)
{
  __shared__ float ev[256];
  const int f32 = flags[0];
  const int v = blockIdx.x, tid = threadIdx.x;
  ev[tid] = gload(emb,(long)v*256+tid,f32);
  __syncthreads();
  #pragma unroll
  for (int j=0;j<4;j++){
    const int g = tid*4+j;
    float a = 0.f;
    #pragma unroll 4
    for (int k=0;k<256;k++) a += ev[k]*gload(Wih0,(long)g*512+256+k,f32);
    int pp = (g>>5)&7, gi = ((g>>8)<<5)|(g&31);
    gep[((size_t)pp*34+v)*128+gi] = a;
  }
}

// ---------------------------------------------------------------------------
// key MLP: keyT[n][q][l]  (unchanged)
// ---------------------------------------------------------------------------
__global__ __launch_bounds__(256) void key_mlp(
    const void* __restrict__ seqs,
    const unsigned short* __restrict__ kW0T, const void* __restrict__ kb0,
    const unsigned short* __restrict__ kW1T, const void* __restrict__ kb1,
    const int* __restrict__ flags,
    unsigned short* __restrict__ keyT)
{
  __shared__ float Xt[16*512];
  __shared__ unsigned short Hd[16*512];
  const int f32 = flags[0];
  const int tid = threadIdx.x;
  const int R0 = blockIdx.x*16;
  for (int i=tid;i<8192;i+=256) Xt[i] = gload(seqs,(long)R0*512+i,f32);
  __syncthreads();
  {
    const int j0 = 2*tid;
    float acc0[16], acc1[16];
    #pragma unroll
    for (int r=0;r<16;r++){ acc0[r]=0.f; acc1[r]=0.f; }
    for (int k=0;k<512;k++){
      ushort2 w = *reinterpret_cast<const ushort2*>(kW0T + (size_t)k*512 + j0);
      float w0=b2f(w.x), w1=b2f(w.y);
      #pragma unroll
      for (int r=0;r<16;r++){ float x = Xt[r*512+k]; acc0[r]+=x*w0; acc1[r]+=x*w1; }
    }
    float b0v=gload(kb0,j0,f32), b1v=gload(kb0,j0+1,f32);
    #pragma unroll
    for (int r=0;r<16;r++){
      Hd[r*512+j0]   = f2b(eluf(acc0[r]+b0v));
      Hd[r*512+j0+1] = f2b(eluf(acc1[r]+b1v));
    }
  }
  __syncthreads();
  {
    const int j = tid & 63;
    const int rbase = tid >> 6;
    float acc[4] = {0.f,0.f,0.f,0.f};
    for (int k=0;k<512;k++){
      float w = b2f(kW1T[(size_t)k*64 + j]);
      #pragma unroll
      for (int m=0;m<4;m++) acc[m] += b2f(Hd[(rbase+4*m)*512 + k]) * w;
    }
    float bv = gload(kb1,j,f32);
    #pragma unroll
    for (int m=0;m<4;m++){
      int R = R0 + rbase + 4*m;
      int l = R >> 6, n = R & 63;
      keyT[((size_t)(n*64 + j))*1024 + l] = f2b(acc[m]+bv);
    }
  }
}

// ---------------------------------------------------------------------------
// value MLP: value[n][l][h]  (unchanged)
// ---------------------------------------------------------------------------
__global__ __launch_bounds__(256) void value_mlp(
    const void* __restrict__ seqs,
    const unsigned short* __restrict__ vW0T, const void* __restrict__ vb0,
    const unsigned short* __restrict__ vW1T, const void* __restrict__ vb1,
    const int* __restrict__ flags,
    unsigned short* __restrict__ value)
{
  __shared__ float Xt[16*512];
  __shared__ float Hd[16*256];
  const int f32 = flags[0];
  const int tid = threadIdx.x;
  const int R0 = blockIdx.x*16;
  for (int i=tid;i<8192;i+=256) Xt[i] = gload(seqs,(long)R0*512+i,f32);
  __syncthreads();
  {
    const int j0 = 2*(tid & 127);
    const int rh = tid >> 7;
    float acc0[8], acc1[8];
    #pragma unroll
    for (int r=0;r<8;r++){ acc0[r]=0.f; acc1[r]=0.f; }
    for (int k=0;k<512;k++){
      ushort2 w = *reinterpret_cast<const ushort2*>(vW0T + (size_t)k*256 + j0);
      float w0=b2f(w.x), w1=b2f(w.y);
      #pragma unroll
      for (int r=0;r<8;r++){ float x = Xt[(rh*8+r)*512+k]; acc0[r]+=x*w0; acc1[r]+=x*w1; }
    }
    float b0v=gload(vb0,j0,f32), b1v=gload(vb0,j0+1,f32);
    #pragma unroll
    for (int r=0;r<8;r++){
      Hd[(rh*8+r)*256+j0]   = eluf(acc0[r]+b0v);
      Hd[(rh*8+r)*256+j0+1] = eluf(acc1[r]+b1v);
    }
  }
  __syncthreads();
  {
    const int j = tid;
    float acc[16];
    #pragma unroll
    for (int r=0;r<16;r++) acc[r]=0.f;
    for (int k=0;k<256;k++){
      float w = b2f(vW1T[(size_t)k*256 + j]);
      #pragma unroll
      for (int r=0;r<16;r++) acc[r] += Hd[r*256+k]*w;
    }
    float bv = gload(vb1,j,f32);
    #pragma unroll
    for (int r=0;r<16;r++){
      int R = R0 + r; int l = R>>6, n = R&63;
      value[((size_t)n*1024 + l)*256 + j] = f2b(acc[r]+bv);
    }
  }
}

__global__ __launch_bounds__(256) void zero_hbuf(ull* __restrict__ f){
  int i = blockIdx.x*256 + threadIdx.x;
  if (i < 115712) f[i] = 0;   // tag 0 matches no round (tags start at 1)
}

// ---------------------------------------------------------------------------
// Decode: 256 blocks x 512 threads, 1 block/CU. bid = g*8 + p (g∈32, p∈8):
// XCD = p -> per-XCD weight slice 384 KB (L2-resident). Block serves TWO
// batch elements n ∈ {2g, 2g+1}, interleaved at stage granularity so every
// mailbox wait is >=1 stage after its publish (latency hidden). Part p owns
// h-cols [32p,32p+32) per layer and l-chunk [128p,128p+128) of attention
// (value chunks in LDS, 2x64 KB). Mailbox per n (ull, tagged):
// H0[256] H1[256] H2[256] PC[8][128] (bf16x2-packed pctx) ST[8][2].
// ---------------------------------------------------------------------------
__global__ __launch_bounds__(512, 1) void speller(
    const unsigned short* __restrict__ keyT,
    const unsigned short* __restrict__ value,
    const unsigned short* __restrict__ Wl0,
    const unsigned short* __restrict__ Wl1,
    const unsigned short* __restrict__ Wl2,
    const unsigned short* __restrict__ qW0T,
    const unsigned short* __restrict__ qW1T,
    const float* __restrict__ bsum_p,
    const float* __restrict__ gep,
    const unsigned short* __restrict__ inithc,
    const unsigned short* __restrict__ initcc,
    const unsigned short* __restrict__ qb0c,
    const unsigned short* __restrict__ qb1c,
    const unsigned short* __restrict__ outWc,
    const unsigned short* __restrict__ outbc,
    const int* __restrict__ labels,
    const int* __restrict__ seq_lens,
    const int* __restrict__ dflags,
    ull* __restrict__ hbw,
    void* __restrict__ out)
{
  extern __shared__ char smem_dyn[];
  unsigned short* vlds = (unsigned short*)smem_dyn;   // [2][128 l][256 h]

  __shared__ float sacc[4096];      // lstm full; attn uses [0..1023] + scratch below
  __shared__ float inc[512];
  __shared__ float garr[128];
  __shared__ float hst[2][4][256];  // per n: h0,h1,h2,ctx
  __shared__ float cloc[2][3][32];
  __shared__ float hsl[2][3][32];
  __shared__ float pcl[2][256];
  __shared__ float so[2][2];        // own {pmax,psum} per n

  // D-phase scratch overlaid in sacc[1024..1752) (lstm never concurrent)
  float* sarr  = sacc + 1024;  // [128]
  float* earr  = sacc + 1152;  // [128]
  float* xq    = sacc + 1280;  // [256]
  float* qv    = sacc + 1536;  // [64]
  float* red   = sacc + 1600;  // [64]
  float* statl = sacc + 1664;  // [16]
  float* wf    = sacc + 1680;  // [8]

  const int tid = threadIdx.x;
  const int g = blockIdx.x >> 3;   // bid = g*8 + p
  const int p = blockIdx.x & 7;
  const int f32o = dflags[0];
  const int i64 = dflags[1];
  const int nn0 = 2*g, nn1 = 2*g+1;
  const int slen0 = i64 ? seq_lens[2*nn0] : seq_lens[nn0];
  const int slen1 = i64 ? seq_lens[2*nn1] : seq_lens[nn1];

  ull* MB[2] = { hbw + (size_t)nn0*1808, hbw + (size_t)nn1*1808 };

  // preload value l-chunks into LDS (once): 2 x 128l x 256h
  {
    uint4* dst = (uint4*)vlds;
    const uint4* s0 = (const uint4*)(value + ((size_t)nn0*1024 + p*128)*256);
    const uint4* s1 = (const uint4*)(value + ((size_t)nn1*1024 + p*128)*256);
    for (int i=tid;i<4096;i+=512){ dst[i] = s0[i]; dst[4096+i] = s1[i]; }
  }
  if (tid < 256){
    #pragma unroll
    for (int l=0;l<3;l++){ float v = b2f(inithc[l*256+tid]); hst[0][l][tid]=v; hst[1][l][tid]=v; }
  }
  if (tid < 32){
    #pragma unroll
    for (int l=0;l<3;l++){ float v = b2f(initcc[l*256 + p*32 + tid]); cloc[0][l][tid]=v; cloc[1][l][tid]=v; }
  }
  __syncthreads();

  auto setinc = [&](const float* a, const float* b){
    if (tid < 256){ inc[tid]=a[tid]; inc[256+tid]=b[tid]; }
    __syncthreads();
  };

  // LSTM: 128-gate slice from inc[512]; own 32-col h slice -> hsl + mailbox.
  auto lstm = [&](int ni, const unsigned short* W, const float* bs, const float* ger,
                  int layer, ull* Hw, unsigned tag){
    const int ks = tid >> 4, go8 = tid & 15;   // 32 k-chunks x 16 gate-octs
    const unsigned short* wp = W + (size_t)p*65536 + (size_t)ks*16*128 + go8*8;
    const float* xin = inc + ks*16;
    float a0=0.f,a1=0.f,a2=0.f,a3=0.f,a4=0.f,a5=0.f,a6=0.f,a7=0.f;
    #pragma unroll
    for (int k=0;k<16;k++){
      float x = xin[k];
      uint4 w = *reinterpret_cast<const uint4*>(wp + (size_t)k*128);
      a0 += x*lo16(w.x); a1 += x*hi16(w.x);
      a2 += x*lo16(w.y); a3 += x*hi16(w.y);
      a4 += x*lo16(w.z); a5 += x*hi16(w.z);
      a6 += x*lo16(w.w); a7 += x*hi16(w.w);
    }
    float* sb = sacc + ks*128 + go8*8;
    sb[0]=a0; sb[1]=a1; sb[2]=a2; sb[3]=a3; sb[4]=a4; sb[5]=a5; sb[6]=a6; sb[7]=a7;
    __syncthreads();
    if (tid < 128){
      float s = bs[tid] + (ger ? ger[tid] : 0.f);
      #pragma unroll
      for (int u=0;u<32;u++) s += sacc[u*128+tid];
      garr[tid] = s;
    }
    __syncthreads();
    if (tid < 32){
      float gi=garr[tid], gf=garr[32+tid], gg=garr[64+tid], go=garr[96+tid];
      float cc = sigf(gf)*cloc[ni][layer][tid] + sigf(gi)*tanhf(gg);
      float hh = sigf(go)*tanhf(cc);
      cloc[ni][layer][tid]=cc;
      hsl[ni][layer][tid]=hh;
      ast64(Hw + p*32 + tid, pk(hh, tag));
    }
    // no trailing barrier; next setinc/gather opens with one
  };

  // gather full 256-h: own slice from LDS, 7 remote slices by tag-poll.
  auto gather_h = [&](int ni, const ull* Hw, int layer, unsigned tag){
    __syncthreads();
    if (tid < 256){
      int sp = tid >> 5; float v;
      if (sp == p) v = hsl[ni][layer][tid & 31];
      else { const ull* w = Hw + tid; ull u = ald64(w);
             while ((unsigned)(u>>32) != tag) u = ald64(w);
             v = upk(u); }
      hst[ni][layer][tid] = v;
    }
    __syncthreads();
  };

  // attention compute: replicated q-MLP from full h2, own 128-l chunk scores,
  // softmax partials + partial ctx -> mailbox (PC bf16x2-packed, ST f32).
  auto attn_comp = [&](int ni, int n, int slen, unsigned tag){
    const float* h2v = hst[ni][2];
    ull* PC = MB[ni] + 768;
    ull* ST = MB[ni] + 1792;
    { // xq partials: 256 cols x 2 k-halves of 128
      const int kh = tid >> 8, j = tid & 255;
      const unsigned short* qp = qW0T + (size_t)(kh*128)*256 + j;
      float a = 0.f;
      #pragma unroll 8
      for (int k=0;k<128;k++) a += h2v[kh*128+k]*b2f(qp[(size_t)k*256]);
      sacc[kh*256 + j] = a;
    }
    __syncthreads();
    if (tid < 256) xq[tid] = eluf(sacc[tid]+sacc[256+tid] + b2f(qb0c[tid]));
    __syncthreads();
    { // qv partials: 64 cols x 8 k-strips of 32
      const int k8 = tid >> 6, qc = tid & 63;
      float a = 0.f;
      const unsigned short* qp = qW1T + qc;
      #pragma unroll 8
      for (int k=0;k<32;k++){ int kk = k8*32+k; a += xq[kk]*b2f(qp[(size_t)kk*64]); }
      sacc[k8*64+qc] = a;
    }
    __syncthreads();
    if (tid < 64){
      float s=0.f;
      #pragma unroll
      for (int u=0;u<8;u++) s += sacc[u*64+tid];
      qv[tid] = s + b2f(qb1c[tid]);
    }
    __syncthreads();
    { // scores own l-chunk (128 l): 64 l-pairs x 8 q-chunks of 8
      const int qh = tid >> 6, lp = tid & 63;
      float a0=0.f,a1=0.f;
      const unsigned short* kp = keyT + (size_t)n*65536 + (size_t)qh*8*1024 + p*128 + 2*lp;
      #pragma unroll
      for (int q=0;q<8;q++){
        ushort2 w = *reinterpret_cast<const ushort2*>(kp + (size_t)q*1024);
        float qq = qv[qh*8+q];
        a0 += qq*b2f(w.x); a1 += qq*b2f(w.y);
      }
      sacc[qh*128+2*lp]=a0; sacc[qh*128+2*lp+1]=a1;
    }
    __syncthreads();
    if (tid < 128){
      float s=0.f;
      #pragma unroll
      for (int u=0;u<8;u++) s += sacc[u*128+tid];
      sarr[tid] = (p*128+tid < slen) ? s : -1e30f;
    }
    __syncthreads();
    if (tid < 64) red[tid] = fmaxf(sarr[tid], sarr[tid+64]);
    __syncthreads();
    for (int s=32;s>0;s>>=1){ if (tid<s) red[tid]=fmaxf(red[tid],red[tid+s]); __syncthreads(); }
    const float pmax = red[0];
    __syncthreads();
    if (tid < 128) earr[tid] = (p*128+tid < slen) ? __expf(sarr[tid]-pmax) : 0.f;
    __syncthreads();
    if (tid < 64) red[tid] = earr[tid]+earr[tid+64];
    __syncthreads();
    for (int s=32;s>0;s>>=1){ if (tid<s) red[tid]+=red[tid+s]; __syncthreads(); }
    const float psum = red[0];
    __syncthreads();
    { // partial ctx from LDS value chunk: 128 h-pairs x 4 l-chunks of 32
      const int lq = tid >> 7, hp = tid & 127;
      float a0=0.f,a1=0.f;
      const unsigned short* vp = vlds + (size_t)ni*32768 + (size_t)(lq*32)*256 + 2*hp;
      #pragma unroll 8
      for (int l=0;l<32;l++){
        ushort2 w = *reinterpret_cast<const ushort2*>(vp + (size_t)l*256);
        float e = earr[lq*32+l];
        a0 += e*b2f(w.x); a1 += e*b2f(w.y);
      }
      sacc[lq*256+2*hp]=a0; sacc[lq*256+2*hp+1]=a1;
    }
    __syncthreads();
    if (tid < 256) pcl[ni][tid] = sacc[tid]+sacc[256+tid]+sacc[512+tid]+sacc[768+tid];
    if (tid == 0){ so[ni][0]=pmax; so[ni][1]=psum; }
    __syncthreads();   // pcl pairs complete before packing
    if (tid < 128) ast64(PC + p*128 + tid, pk2(pcl[ni][2*tid], pcl[ni][2*tid+1], tag));
    if (tid == 0){ ast64(ST + p*2, pk(pmax, tag)); ast64(ST + p*2 + 1, pk(psum, tag)); }
  };

  // attention finalize: gather stats + packed pctx, exact softmax assembly.
  auto attn_fin = [&](int ni, unsigned tag){
    ull* PC = MB[ni] + 768;
    ull* ST = MB[ni] + 1792;
    __syncthreads();   // protect statl/wf scratch reuse
    if (tid < 16){
      int q = tid >> 1, ix = tid & 1; float v;
      if (q == p) v = so[ni][ix];
      else { const ull* w = ST + q*2 + ix; ull u = ald64(w);
             while ((unsigned)(u>>32) != tag) u = ald64(w);
             v = upk(u); }
      statl[tid] = v;
    }
    __syncthreads();
    if (tid == 0){
      float M = -1e30f;
      #pragma unroll
      for (int q=0;q<8;q++) M = fmaxf(M, statl[2*q]);
      float wq[8], s=0.f;
      #pragma unroll
      for (int q=0;q<8;q++){ wq[q] = __expf(statl[2*q]-M); s += statl[2*q+1]*wq[q]; }
      float inv = 1.f/s;
      #pragma unroll
      for (int q=0;q<8;q++) wf[q] = wq[q]*inv;
    }
    __syncthreads();
    if (tid < 256){
      float acc = pcl[ni][tid]*wf[p];
      const int half = tid & 1, wi = tid >> 1;
      #pragma unroll
      for (int q=0;q<8;q++){
        if (q == p) continue;
        const ull* w = PC + q*128 + wi; ull u = ald64(w);
        while ((unsigned)(u>>32) != tag) u = ald64(w);
        unsigned short bits = half ? (unsigned short)(u & 0xffff)
                                   : (unsigned short)((u>>16) & 0xffff);
        acc += b2f(bits)*wf[q];
      }
      hst[ni][3][tid] = acc;
    }
    __syncthreads();
  };

  // out projection: rows r = p + 8*ri (ri<4), rows 32/33 on parts 0/1.
  auto outproj = [&](int ni, int n, int t){
    const float* cv = hst[ni][3]; const float* h2v = hst[ni][2];
    const int ri = tid >> 6, kk = tid & 63;
    int r = -1;
    if (ri < 4) r = p + 8*ri;
    else if (ri == 4 && p < 2) r = 32 + p;
    if (r >= 0){
      const unsigned short* wr = outWc + (size_t)r*512 + kk;
      float acc = 0.f;
      #pragma unroll
      for (int s=0;s<4;s++) acc += cv[s*64+kk]*b2f(wr[s*64]);
      #pragma unroll
      for (int s=0;s<4;s++) acc += h2v[s*64+kk]*b2f(wr[256+s*64]);
      #pragma unroll
      for (int off=32; off>0; off>>=1) acc += __shfl_down(acc, off);
      if (kk==0){
        float v = acc + b2f(outbc[r]);
        size_t oi = ((size_t)(t*64+n))*34 + r;
        if (f32o) ((float*)out)[oi]=v; else ((unsigned short*)out)[oi]=f2b(v);
      }
    }
  };

  // initial prev_ctx from inith[2] (h2 local in all blocks -> no gather)
  attn_comp(0, nn0, slen0, 1);
  attn_comp(1, nn1, slen1, 1);
  attn_fin(0, 1);
  attn_fin(1, 1);

  for (int t=0;t<256;t++){
    const unsigned tb = 4*(unsigned)t;
    const int lab0 = i64 ? labels[2*(t*64+nn0)] : labels[t*64+nn0];
    const int lab1 = i64 ? labels[2*(t*64+nn1)] : labels[t*64+nn1];
    // stage A (L0): input {ctx, h0_prev}
    setinc(hst[0][3], hst[0][0]);
    lstm(0, Wl0, bsum_p + p*128, gep + ((size_t)p*34+lab0)*128, 0, MB[0], tb+2);
    setinc(hst[1][3], hst[1][0]);
    lstm(1, Wl0, bsum_p + p*128, gep + ((size_t)p*34+lab1)*128, 0, MB[1], tb+2);
    // stage B (L1): input {h0_new, h1_prev}; A-gathers hidden behind peer stage
    gather_h(0, MB[0], 0, tb+2);
    setinc(hst[0][0], hst[0][1]);
    lstm(0, Wl1, bsum_p + 1024 + p*128, nullptr, 1, MB[0]+256, tb+3);
    gather_h(1, MB[1], 0, tb+2);
    setinc(hst[1][0], hst[1][1]);
    lstm(1, Wl1, bsum_p + 1024 + p*128, nullptr, 1, MB[1]+256, tb+3);
    // stage C (L2): input {h1_new, h2_prev}
    gather_h(0, MB[0]+256, 1, tb+3);
    setinc(hst[0][1], hst[0][2]);
    lstm(0, Wl2, bsum_p + 2048 + p*128, nullptr, 2, MB[0]+512, tb+4);
    gather_h(1, MB[1]+256, 1, tb+3);
    setinc(hst[1][1], hst[1][2]);
    lstm(1, Wl2, bsum_p + 2048 + p*128, nullptr, 2, MB[1]+512, tb+4);
    // stage D: attention
    gather_h(0, MB[0]+512, 2, tb+4);
    attn_comp(0, nn0, slen0, tb+5);
    gather_h(1, MB[1]+512, 2, tb+4);
    attn_comp(1, nn1, slen1, tb+5);
    attn_fin(0, tb+5);
    outproj(0, nn0, t);
    attn_fin(1, tb+5);
    outproj(1, nn1, t);
  }
}

extern "C" void kernel_launch(void* const* d_in, const int* in_sizes, int n_in,
                              void* d_out, int out_size, void* d_ws, size_t ws_size,
                              hipStream_t stream) {
  const void* seqs  = d_in[0];
  const int* seq_lens = (const int*)d_in[1];
  const int* labels   = (const int*)d_in[2];
  const void* emb   = d_in[3];
  const void* inith = d_in[4];
  const void* initc = d_in[5];
  const void* Wih0 = d_in[6];  const void* Whh0 = d_in[7];
  const void* bih0 = d_in[8];  const void* bhh0 = d_in[9];
  const void* Wih1 = d_in[10]; const void* Whh1 = d_in[11];
  const void* bih1 = d_in[12]; const void* bhh1 = d_in[13];
  const void* Wih2 = d_in[14]; const void* Whh2 = d_in[15];
  const void* bih2 = d_in[16]; const void* bhh2 = d_in[17];
  const void* qW0 = d_in[18];  const void* qb0 = d_in[19];
  const void* qW1 = d_in[20];  const void* qb1 = d_in[21];
  const void* kW0 = d_in[22];  const void* kb0 = d_in[23];
  const void* kW1 = d_in[24];  const void* kb1 = d_in[25];
  const void* vW0 = d_in[26];  const void* vb0 = d_in[27];
  const void* vW1 = d_in[28];  const void* vb1 = d_in[29];
  const void* outW = d_in[30]; const void* outb = d_in[31];

  char* ws = (char*)d_ws;
  unsigned short* keyT  = (unsigned short*)(ws);             //  8,388,608 B  [64][64][1024]
  unsigned short* value = (unsigned short*)(ws + 8388608);   // 33,554,432 B  [64][1024][256]
  unsigned short* Wl0   = (unsigned short*)(ws + 41943040);  //  1,048,576 B  [8][512][128]
  unsigned short* Wl1   = (unsigned short*)(ws + 42991616);
  unsigned short* Wl2   = (unsigned short*)(ws + 44040192);
  unsigned short* kW0T  = (unsigned short*)(ws + 45088768);  //    524,288 B (prep-only)
  unsigned short* kW1T  = (unsigned short*)(ws + 45613056);  //     65,536 B (prep-only)
  unsigned short* vW0T  = (unsigned short*)(ws + 45678592);  //    262,144 B (prep-only)
  unsigned short* vW1T  = (unsigned short*)(ws + 45940736);  //    131,072 B (prep-only)
  unsigned short* qW0T  = (unsigned short*)(ws + 46071808);  //    131,072 B
  unsigned short* qW1T  = (unsigned short*)(ws + 46202880);  //     32,768 B
  float*          bsum  = (float*)(ws + 46235648);           //     12,288 B  [3][8][128]
  float*          gep   = (float*)(ws + 46247936);           //    139,264 B  [8][34][128]
  unsigned short* outWc = (unsigned short*)(ws + 46387200);  //     34,816 B
  unsigned short* inithc= (unsigned short*)(ws + 46422016);  //      1,536 B
  unsigned short* initcc= (unsigned short*)(ws + 46423552);  //      1,536 B
  unsigned short* qb0c  = (unsigned short*)(ws + 46425088);  //        512 B
  unsigned short* qb1c  = (unsigned short*)(ws + 46425600);  //        128 B
  unsigned short* outbc = (unsigned short*)(ws + 46425728);  //        128 B
  int*            dflags= (int*)(ws + 46425856);             //         16 B
  // tagged mailbox overlaps kW0T..vW1T (prep-only, consumed before speller):
  // 64 n x 1808 ull = 925,696 B <= 983,040 B available
  ull* hbw = (ull*)(ws + 45088768);

  sniff<<<dim3(1), dim3(64), 0, stream>>>(seqs, seq_lens, dflags);
  prep_transpose<<<dim3(8472), dim3(256), 0, stream>>>(
      Wih0,Whh0,Wih1,Whh1,Wih2,Whh2, kW0,kW1,vW0,vW1,qW0,qW1,
      bih0,bhh0,bih1,bhh1,bih2,bhh2,
      outW,inith,initc,qb0,qb1,outb, dflags,
      Wl0,Wl1,Wl2,kW0T,kW1T,vW0T,vW1T,qW0T,qW1T,bsum,
      outWc,inithc,initcc,qb0c,qb1c,outbc);
  prep_ge<<<dim3(34), dim3(256), 0, stream>>>(emb, Wih0, dflags, gep);
  key_mlp<<<dim3(4096), dim3(256), 0, stream>>>(seqs, kW0T, kb0, kW1T, kb1, dflags, keyT);
  value_mlp<<<dim3(4096), dim3(256), 0, stream>>>(seqs, vW0T, vb0, vW1T, vb1, dflags, value);
  zero_hbuf<<<dim3(452), dim3(256), 0, stream>>>(hbw);
  hipFuncSetAttribute((const void*)speller, hipFuncAttributeMaxDynamicSharedMemorySize, 131072);
  speller<<<dim3(256), dim3(512), 131072, stream>>>(
      keyT, value, Wl0, Wl1, Wl2, qW0T, qW1T, bsum, gep,
      inithc, initcc, qb0c, qb1c, outWc, outbc, labels, seq_lens, dflags,
      hbw, d_out);
}